// Round 23
// baseline (104.822 us; speedup 1.0000x reference)
//
#include <hip/hip_runtime.h>
#include <hip/hip_bf16.h>
#include <cstdint>
#include <cstddef>

#define B_  2
#define T_  2048
#define D_  1024
#define H_  16
#define M_  (B_*T_)   // 4096 rows total

typedef __bf16 bf16_t;
typedef __attribute__((ext_vector_type(8))) __bf16 bf16x8;
typedef __attribute__((ext_vector_type(4))) __bf16 bf16x4;
typedef __attribute__((ext_vector_type(4))) float f32x4;
typedef __attribute__((ext_vector_type(16))) float f32x16;
typedef unsigned int u32;
typedef __attribute__((ext_vector_type(4))) u32 u32x4;

#define MFMA16(a,b,c) __builtin_amdgcn_mfma_f32_16x16x32_bf16(a,b,c,0,0,0)
#define MFMA32(a,b,c) __builtin_amdgcn_mfma_f32_32x32x16_bf16(a,b,c,0,0,0)
#define EXP2(x) __builtin_amdgcn_exp2f(x)

#define QSCALE 0.18033688011112042f
#define DEFER_THR 10.0f

__device__ inline void async16(const void* g, void* l) {
  __builtin_amdgcn_global_load_lds((const __attribute__((address_space(1))) void*)g,
                                   (__attribute__((address_space(3))) void*)l, 16, 0, 0);
}

__device__ __forceinline__ f32x16 zero16() {
  f32x16 z;
  #pragma unroll
  for (int i = 0; i < 16; ++i) z[i] = 0.f;
  return z;
}

__device__ __forceinline__ u32 pk2(float lo, float hi) {
  u32 a = __builtin_bit_cast(unsigned short, (__bf16)lo);
  u32 b = __builtin_bit_cast(unsigned short, (__bf16)hi);
  return a | (b << 16);
}
__device__ __forceinline__ float xswap_max(float x) {
  return fmaxf(x, __shfl_xor(x, 32));
}
__device__ __forceinline__ float xswap_sum(float x) {
  return x + __shfl_xor(x, 32);
}

// ---------------- fused cast kernel ----------------
__global__ __launch_bounds__(256) void cast_all_k(const float* __restrict__ x,
                                                  const float* __restrict__ wq,
                                                  const float* __restrict__ wk,
                                                  const float* __restrict__ wv,
                                                  const float* __restrict__ wo,
                                                  bf16_t* __restrict__ xb,
                                                  bf16_t* __restrict__ wbase) {
  int bid = blockIdx.x;
  const float* src;
  bf16_t* dst;
  float sc = 1.0f;
  int i;
  if (bid < 2048) {
    src = x; dst = xb; i = bid * 256 + threadIdx.x;
  } else {
    int wsel = (bid - 2048) >> 9;
    int wblk = (bid - 2048) & 511;
    src = wsel == 0 ? wq : wsel == 1 ? wk : wsel == 2 ? wv : wo;
    if (wsel == 0) sc = QSCALE;
    dst = wbase + (size_t)wsel * D_ * D_;
    i = wblk * 256 + threadIdx.x;
  }
  const float4* p = (const float4*)src + 2 * (size_t)i;
  float4 a = p[0], b = p[1];
  bf16x8 r = { (__bf16)(a.x*sc), (__bf16)(a.y*sc), (__bf16)(a.z*sc), (__bf16)(a.w*sc),
               (__bf16)(b.x*sc), (__bf16)(b.y*sc), (__bf16)(b.z*sc), (__bf16)(b.w*sc) };
  *((bf16x8*)dst + i) = r;
}

// ============ 128x256 BK=32 QKV GEMM, 8 waves, TRIPLE-buffered 2-deep ============
// r23: 1-deep prefetch left ~20% stall (stage latency 500-900cy > ~300cy
// compute phase). Triple buffer (3 x 24KB = 72KB, still 2 blocks/CU): per
// tile t stage t+2, wait vmcnt(6) (= t+1's 3 + t+2's 3 outstanding, drains
// tile-t's 3) -> stage latency spans TWO compute phases (T4 counted-vmcnt).
// WAR: buf (t+2)%3 last read at tile t-1, whose end barrier precedes stage.
// z=2 (V) fused transpose epilogue (r22). No setprio (m190).
__global__ __launch_bounds__(512) void qkv8_k(const bf16_t* __restrict__ xb,
                                              const bf16_t* __restrict__ wqkv,
                                              bf16_t* __restrict__ Qbase,
                                              bf16_t* __restrict__ Vt) {
  __shared__ __align__(16) char lds[73728];
  const int z = blockIdx.z;
  const bf16_t* W = wqkv + (size_t)z * D_ * D_;
  bf16_t* C = Qbase + (size_t)z * M_ * D_;
  const int brow = blockIdx.x * 128, bcol = blockIdx.y * 256;

  const int tid = threadIdx.x;
  const int lane = tid & 63, w = tid >> 6;
  const int wm = w >> 2, wn = w & 3;
  const int lo = lane & 15, hi4 = lane >> 4;

  f32x4 acc[4][4];
  #pragma unroll
  for (int mi = 0; mi < 4; ++mi)
    #pragma unroll
    for (int ni = 0; ni < 4; ++ni) acc[mi][ni] = (f32x4){0.f, 0.f, 0.f, 0.f};

#define QSTAGE(T, BUF)                                                        \
  {                                                                           \
    char* base = lds + (BUF) * 24576;                                         \
    const int kt = (T) * 32;                                                  \
    {                                                                         \
      int c = tid;                                                            \
      int row = c >> 2, sl = c & 3;                                           \
      int slg = sl ^ ((row >> 1) & 3);                                        \
      async16(xb + (size_t)(brow + row) * D_ + kt + slg * 8, base + c * 16);  \
    }                                                                         \
    _Pragma("unroll")                                                         \
    for (int i2 = 0; i2 < 2; ++i2) {                                          \
      int c = i2 * 512 + tid;                                                 \
      int row = c >> 2, sl = c & 3;                                           \
      int slg = sl ^ ((row >> 1) & 3);                                        \
      async16(W + (size_t)(bcol + row) * D_ + kt + slg * 8,                   \
              base + 8192 + c * 16);                                          \
    }                                                                         \
  }

  QSTAGE(0, 0)
  QSTAGE(1, 1)

  const int nT = D_ / 32;   // 32 K-tiles
  int buf = 0;              // buffer of tile t; (t+2) goes to (buf+2)%3
  for (int t = 0; t < nT; ++t) {
    const char* Ab = lds + buf * 24576;
    const char* Bb = Ab + 8192;

    if (t + 2 < nT) {
      int nb = buf + 2; if (nb >= 3) nb -= 3;
      QSTAGE(t + 2, nb)
      asm volatile("s_waitcnt vmcnt(6)" ::: "memory");
    } else if (t + 1 < nT) {
      asm volatile("s_waitcnt vmcnt(3)" ::: "memory");
    } else {
      asm volatile("s_waitcnt vmcnt(0)" ::: "memory");
    }
    __builtin_amdgcn_s_barrier();

    bf16x8 af[4], bf[4];
    #pragma unroll
    for (int mi = 0; mi < 4; ++mi) {
      int row = wm * 64 + mi * 16 + lo;
      af[mi] = *(const bf16x8*)(Ab + row * 64 + ((hi4 ^ ((row >> 1) & 3)) << 4));
    }
    #pragma unroll
    for (int ni = 0; ni < 4; ++ni) {
      int row = wn * 64 + ni * 16 + lo;
      bf[ni] = *(const bf16x8*)(Bb + row * 64 + ((hi4 ^ ((row >> 1) & 3)) << 4));
    }
    #pragma unroll
    for (int mi = 0; mi < 4; ++mi)
      #pragma unroll
      for (int ni = 0; ni < 4; ++ni)
        acc[mi][ni] = MFMA16(af[mi], bf[ni], acc[mi][ni]);

    __builtin_amdgcn_s_barrier();
    ++buf; if (buf == 3) buf = 0;
  }
#undef QSTAGE

  if (z == 2) {
    // V slice: write transposed. b uniform per block (128 | 2048).
    const int b2 = brow >> 11;
    #pragma unroll
    for (int mi = 0; mi < 4; ++mi)
      #pragma unroll
      for (int ni = 0; ni < 4; ++ni) {
        int row = brow + wm * 64 + mi * 16 + hi4 * 4;   // V row (= b2*2048 + t0)
        int col = bcol + wn * 64 + ni * 16 + lo;        // V col (= h*64 + dh)
        int t0 = row & (T_ - 1);
        bf16_t* dst = Vt + ((size_t)((b2 * 16 + (col >> 6)) * 64 + (col & 63))) * T_ + t0;
        bf16x4 v = { (__bf16)acc[mi][ni][0], (__bf16)acc[mi][ni][1],
                     (__bf16)acc[mi][ni][2], (__bf16)acc[mi][ni][3] };
        *(bf16x4*)dst = v;
      }
  } else {
    #pragma unroll
    for (int mi = 0; mi < 4; ++mi)
      #pragma unroll
      for (int ni = 0; ni < 4; ++ni)
        #pragma unroll
        for (int i = 0; i < 4; ++i) {
          int row = brow + wm * 64 + mi * 16 + hi4 * 4 + i;
          int col = bcol + wn * 64 + ni * 16 + lo;
          C[(size_t)row * D_ + col] = (bf16_t)acc[mi][ni][i];
        }
  }
}

// ============ 64x128 BK=32 OUT GEMM, 4 waves, 512 blocks (r20, frozen) ============
__global__ __launch_bounds__(256) void out64_k(const bf16_t* __restrict__ O,
                                               const bf16_t* __restrict__ wob,
                                               float* __restrict__ Y) {
  __shared__ __align__(16) char lds[24576];
  const int brow = blockIdx.x * 64, bcol = blockIdx.y * 128;

  const int tid = threadIdx.x;
  const int lane = tid & 63, w = tid >> 6;
  const int wm = w >> 1, wn = w & 1;
  const int lo = lane & 15, hi4 = lane >> 4;

  f32x4 acc[2][4];
  #pragma unroll
  for (int mi = 0; mi < 2; ++mi)
    #pragma unroll
    for (int ni = 0; ni < 4; ++ni) acc[mi][ni] = (f32x4){0.f, 0.f, 0.f, 0.f};

#define OSTAGE(T)                                                             \
  {                                                                           \
    char* base = lds + ((T) & 1) * 12288;                                     \
    const int kt = (T) * 32;                                                  \
    {                                                                         \
      int c = tid;                                                            \
      int row = c >> 2, sl = c & 3;                                           \
      int slg = sl ^ ((row >> 1) & 3);                                        \
      async16(O + (size_t)(brow + row) * D_ + kt + slg * 8, base + c * 16);   \
    }                                                                         \
    _Pragma("unroll")                                                         \
    for (int i2 = 0; i2 < 2; ++i2) {                                          \
      int c = i2 * 256 + tid;                                                 \
      int row = c >> 2, sl = c & 3;                                           \
      int slg = sl ^ ((row >> 1) & 3);                                        \
      async16(wob + (size_t)(bcol + row) * D_ + kt + slg * 8,                 \
              base + 4096 + c * 16);                                          \
    }                                                                         \
  }

  OSTAGE(0)

  const int nT = D_ / 32;
  for (int t = 0; t < nT; ++t) {
    const char* Ab = lds + (t & 1) * 12288;
    const char* Bb = Ab + 4096;

    if (t + 1 < nT) {
      OSTAGE(t + 1)
      asm volatile("s_waitcnt vmcnt(3)" ::: "memory");
    } else {
      asm volatile("s_waitcnt vmcnt(0)" ::: "memory");
    }
    __builtin_amdgcn_s_barrier();

    bf16x8 af[2], bf[4];
    #pragma unroll
    for (int mi = 0; mi < 2; ++mi) {
      int row = wm * 32 + mi * 16 + lo;
      af[mi] = *(const bf16x8*)(Ab + row * 64 + ((hi4 ^ ((row >> 1) & 3)) << 4));
    }
    #pragma unroll
    for (int ni = 0; ni < 4; ++ni) {
      int row = wn * 64 + ni * 16 + lo;
      bf[ni] = *(const bf16x8*)(Bb + row * 64 + ((hi4 ^ ((row >> 1) & 3)) << 4));
    }
    #pragma unroll
    for (int mi = 0; mi < 2; ++mi)
      #pragma unroll
      for (int ni = 0; ni < 4; ++ni)
        acc[mi][ni] = MFMA16(af[mi], bf[ni], acc[mi][ni]);

    __builtin_amdgcn_s_barrier();
  }
#undef OSTAGE

  #pragma unroll
  for (int mi = 0; mi < 2; ++mi)
    #pragma unroll
    for (int ni = 0; ni < 4; ++ni)
      #pragma unroll
      for (int i = 0; i < 4; ++i) {
        int row = brow + wm * 32 + mi * 16 + hi4 * 4 + i;
        int col = bcol + wn * 64 + ni * 16 + lo;
        Y[(size_t)row * D_ + col] = acc[mi][ni][i];
      }
}

// ---------------- flash attention: r13 structure (proven 41.8-42.2us, FROZEN) ----------------
__global__ __launch_bounds__(512) void attn_k(const bf16_t* __restrict__ Q,
                                              const bf16_t* __restrict__ K,
                                              const bf16_t* __restrict__ Vt,
                                              bf16_t* __restrict__ O) {
  const int bh = blockIdx.x, b = bh >> 4, h = bh & 15;
  const int yy = (int)blockIdx.y;
  const int qt = (yy < 8) ? (15 - 2 * yy) : (30 - 2 * yy);
  const int tid = threadIdx.x;

  __shared__ __align__(16) char smem[65536];

  const bf16_t* Kt0 = K + ((size_t)b * T_) * D_ + h * 64;
  const bf16_t* Vt0 = Vt + (size_t)bh * 64 * T_;

  const int lane = tid & 63, w = tid >> 6;
  const int wl = w & 3, wg = w >> 2;
  const int ln = lane & 31, hi = lane >> 5;
  const int tl = tid & 255;
  const int tau = (ln & ~12) | (((ln & 4) << 1) | ((ln & 8) >> 1));
  char* sgbase = smem + ((tid >= 256) ? 32768 : 0);
  char* cgbase = smem + wg * 32768;
  float* mo = (float*)smem;
  float* ml = (float*)(smem + 33792);

  const int q_abs = qt * 128 + wl * 32 + ln;
  bf16x8 qf[4];
  {
    const bf16_t* Qrow = Q + ((size_t)b * T_ + q_abs) * D_ + h * 64;
    #pragma unroll
    for (int ks = 0; ks < 4; ++ks)
      qf[ks] = *(const bf16x8*)(Qrow + ks * 16 + hi * 8);
  }

  f32x16 o0 = zero16(), o1 = zero16();
  float m = -1e30f, l = 0.f;

  const int jc    = qt + 1;
  const int jd    = 2 * qt + (wl >> 1);
  const int tbase = wg ? (qt + 1) : 0;

#define STAGE8(BUF, TT)                                                       \
  {                                                                           \
    char* kd = sgbase + (BUF) * 8192;                                         \
    char* vd = sgbase + 16384 + (BUF) * 8192;                                 \
    _Pragma("unroll")                                                         \
    for (int it = 0; it < 2; ++it) {                                          \
      int c = it * 256 + tl;                                                  \
      int row = c >> 3, sl = c & 7;                                           \
      int slg = sl ^ (row & 7);                                               \
      async16(Kt0 + ((size_t)((TT) * 64 + row)) * D_ + slg * 8, kd + c * 16); \
      async16(Vt0 + (size_t)row * T_ + (TT) * 64 + slg * 8, vd + c * 16);     \
    }                                                                         \
  }

#define PACK_PV8(PS, KS, VB)                                                  \
  {                                                                           \
    const int r0 = ((KS) & 1) * 8;                                            \
    u32x4 pw = {pk2((PS)[r0 + 0], (PS)[r0 + 1]),                              \
                pk2((PS)[r0 + 2], (PS)[r0 + 3]),                              \
                pk2((PS)[r0 + 4], (PS)[r0 + 5]),                              \
                pk2((PS)[r0 + 6], (PS)[r0 + 7])};                             \
    bf16x8 pb = __builtin_bit_cast(bf16x8, pw);                               \
    const int sg = (KS) * 2 + hi;                                             \
    int row = ln;                                                             \
    bf16x8 vf0 = *(const bf16x8*)((VB) + row * 64 + ((sg ^ (row & 7)) * 8));  \
    o0 = MFMA32(vf0, pb, o0);                                                 \
    row = 32 + ln;                                                            \
    bf16x8 vf1 = *(const bf16x8*)((VB) + row * 64 + ((sg ^ (row & 7)) * 8));  \
    o1 = MFMA32(vf1, pb, o1);                                                 \
  }

  STAGE8(0, tbase)
  int cur = 0;
  for (int j = 0; j < jc; ++j) {
    if (j + 1 < jc) {
      STAGE8(cur ^ 1, tbase + j + 1)
      asm volatile("s_waitcnt vmcnt(4)" ::: "memory");
    } else {
      asm volatile("s_waitcnt vmcnt(0)" ::: "memory");
    }
    __builtin_amdgcn_s_barrier();

    const int tt = tbase + j;
    if (tt <= jd) {
      const bf16_t* Kb = (const bf16_t*)(cgbase + cur * 8192);
      const bf16_t* Vb = (const bf16_t*)(cgbase + 16384 + cur * 8192);
      f32x16 s0 = zero16(), s1 = zero16();
      __builtin_amdgcn_s_setprio(1);
      #pragma unroll
      for (int ks = 0; ks < 4; ++ks) {
        const int sg = ks * 2 + hi;
        int row = tau;
        bf16x8 kf0 = *(const bf16x8*)(Kb + row * 64 + ((sg ^ (row & 7)) * 8));
        s0 = MFMA32(kf0, qf[ks], s0);
        row = 32 + tau;
        bf16x8 kf1 = *(const bf16x8*)(Kb + row * 64 + ((sg ^ (row & 7)) * 8));
        s1 = MFMA32(kf1, qf[ks], s1);
      }
      __builtin_amdgcn_s_setprio(0);
      if (tt == jd) {
        const int kv0 = tt * 64;
        #pragma unroll
        for (int r = 0; r < 16; ++r) {
          const int pos = (r & 7) + 16 * (r >> 3) + 8 * hi;
          if (kv0 + pos      > q_abs) s0[r] = -3e38f;
          if (kv0 + 32 + pos > q_abs) s1[r] = -3e38f;
        }
      }
      float t[16];
      #pragma unroll
      for (int r = 0; r < 16; ++r) t[r] = fmaxf(s0[r], s1[r]);
      #pragma unroll
      for (int st = 8; st >= 1; st >>= 1)
        #pragma unroll
        for (int i = 0; i < st; ++i) t[i] = fmaxf(t[i], t[i + st]);
      float pmax = xswap_max(t[0]);
      if (!__all(pmax - m <= DEFER_THR)) {
        float mn   = fmaxf(m, pmax);
        float corr = EXP2(m - mn);
        m = mn;
        l *= corr;
        #pragma unroll
        for (int r = 0; r < 16; ++r) { o0[r] *= corr; o1[r] *= corr; }
      }
      float u[16];
      #pragma unroll
      for (int r = 0; r < 16; ++r) {
        float p0 = EXP2(s0[r] - m); s0[r] = p0;
        float p1 = EXP2(s1[r] - m); s1[r] = p1;
        u[r] = p0 + p1;
      }
      #pragma unroll
      for (int st = 8; st >= 1; st >>= 1)
        #pragma unroll
        for (int i = 0; i < st; ++i) u[i] += u[i + st];
      l += xswap_sum(u[0]);
      __builtin_amdgcn_s_setprio(1);
      PACK_PV8(s0, 0, Vb)
      PACK_PV8(s0, 1, Vb)
      PACK_PV8(s1, 2, Vb)
      PACK_PV8(s1, 3, Vb)
      __builtin_amdgcn_s_setprio(0);
    }
    __builtin_amdgcn_s_barrier();
    cur ^= 1;
  }

  if (wg == 1) {
    float* mop = mo + ((size_t)wl * 64 + lane) * 33;
    #pragma unroll
    for (int r = 0; r < 16; ++r) { mop[r] = o0[r]; mop[16 + r] = o1[r]; }
    float* mlp = ml + ((size_t)wl * 64 + lane) * 2;
    mlp[0] = m; mlp[1] = l;
  }
  __syncthreads();
  if (wg == 0) {
    const float* mop = mo + ((size_t)wl * 64 + lane) * 33;
    const float* mlp = ml + ((size_t)wl * 64 + lane) * 2;
    float mB = mlp[0], lB = mlp[1];
    float mS = fmaxf(m, mB);
    float cA = EXP2(m - mS), cB = EXP2(mB - mS);
    float lS = l * cA + lB * cB;
    float rl = 1.0f / lS;
    bf16_t* Orow = O + ((size_t)b * T_ + q_abs) * D_ + h * 64;
    #pragma unroll
    for (int g = 0; g < 4; ++g) {
      const int dh0 = 8 * g + 4 * hi;
      bf16x4 v0, v1;
      #pragma unroll
      for (int jj = 0; jj < 4; ++jj) {
        v0[jj] = (__bf16)((o0[4 * g + jj] * cA + mop[4 * g + jj] * cB) * rl);
        v1[jj] = (__bf16)((o1[4 * g + jj] * cA + mop[16 + 4 * g + jj] * cB) * rl);
      }
      *(bf16x4*)(Orow + dh0)      = v0;
      *(bf16x4*)(Orow + 32 + dh0) = v1;
    }
  }
#undef STAGE8
#undef PACK_PV8
}

// ---------------- launcher ----------------
extern "C" void kernel_launch(void* const* d_in, const int* in_sizes, int n_in,
                              void* d_out, int out_size, void* d_ws, size_t ws_size,
                              hipStream_t stream) {
  const float* x  = (const float*)d_in[0];
  const float* wq = (const float*)d_in[1];
  const float* wk = (const float*)d_in[2];
  const float* wv = (const float*)d_in[3];
  const float* wo = (const float*)d_in[4];
  float* out = (float*)d_out;

  char* ws = (char*)d_ws;
  bf16_t* xb  = (bf16_t*)(ws);                       // 8 MB
  bf16_t* wqb = (bf16_t*)(ws + (size_t)( 8 << 20));  // 2 MB each (contiguous qkv+o)
  bf16_t* wob = (bf16_t*)(ws + (size_t)(14 << 20));
  bf16_t* Qb  = (bf16_t*)(ws + (size_t)(16 << 20));  // 8 MB each, Q/K contiguous
  bf16_t* Kb  = (bf16_t*)(ws + (size_t)(24 << 20));
  bf16_t* Ob  = (bf16_t*)(ws + (size_t)(32 << 20));  // attn output
  bf16_t* Vtb = (bf16_t*)(ws + (size_t)(40 << 20));

  (void)in_sizes; (void)n_in; (void)out_size; (void)ws_size;

  cast_all_k<<<dim3(4096), 256, 0, stream>>>(x, wq, wk, wv, wo, xb, wqb);
  qkv8_k<<<dim3(M_ / 128, D_ / 256, 3), 512, 0, stream>>>(xb, wqb, Qb, Vtb);
  attn_k<<<dim3(B_ * H_, T_ / 128), 512, 0, stream>>>(Qb, Kb, Vtb, Ob);
  out64_k<<<dim3(M_ / 64, D_ / 128), 256, 0, stream>>>(Ob, wob, out);
}

// Round 24
// 102.307 us; speedup vs baseline: 1.0246x; 1.0246x over previous
//
#include <hip/hip_runtime.h>
#include <hip/hip_bf16.h>
#include <cstdint>
#include <cstddef>

#define B_  2
#define T_  2048
#define D_  1024
#define H_  16
#define M_  (B_*T_)   // 4096 rows total

typedef __bf16 bf16_t;
typedef __attribute__((ext_vector_type(8))) __bf16 bf16x8;
typedef __attribute__((ext_vector_type(4))) __bf16 bf16x4;
typedef __attribute__((ext_vector_type(4))) float f32x4;
typedef __attribute__((ext_vector_type(16))) float f32x16;
typedef unsigned int u32;
typedef __attribute__((ext_vector_type(4))) u32 u32x4;

#define MFMA16(a,b,c) __builtin_amdgcn_mfma_f32_16x16x32_bf16(a,b,c,0,0,0)
#define MFMA32(a,b,c) __builtin_amdgcn_mfma_f32_32x32x16_bf16(a,b,c,0,0,0)
#define EXP2(x) __builtin_amdgcn_exp2f(x)

#define QSCALE 0.18033688011112042f
#define DEFER_THR 10.0f

__device__ inline void async16(const void* g, void* l) {
  __builtin_amdgcn_global_load_lds((const __attribute__((address_space(1))) void*)g,
                                   (__attribute__((address_space(3))) void*)l, 16, 0, 0);
}

__device__ __forceinline__ f32x16 zero16() {
  f32x16 z;
  #pragma unroll
  for (int i = 0; i < 16; ++i) z[i] = 0.f;
  return z;
}

__device__ __forceinline__ u32 pk2(float lo, float hi) {
  u32 a = __builtin_bit_cast(unsigned short, (__bf16)lo);
  u32 b = __builtin_bit_cast(unsigned short, (__bf16)hi);
  return a | (b << 16);
}
__device__ __forceinline__ float xswap_max(float x) {
  return fmaxf(x, __shfl_xor(x, 32));
}
__device__ __forceinline__ float xswap_sum(float x) {
  return x + __shfl_xor(x, 32);
}

// ---------------- fused cast kernel ----------------
__global__ __launch_bounds__(256) void cast_all_k(const float* __restrict__ x,
                                                  const float* __restrict__ wq,
                                                  const float* __restrict__ wk,
                                                  const float* __restrict__ wv,
                                                  const float* __restrict__ wo,
                                                  bf16_t* __restrict__ xb,
                                                  bf16_t* __restrict__ wbase) {
  int bid = blockIdx.x;
  const float* src;
  bf16_t* dst;
  float sc = 1.0f;
  int i;
  if (bid < 2048) {
    src = x; dst = xb; i = bid * 256 + threadIdx.x;
  } else {
    int wsel = (bid - 2048) >> 9;
    int wblk = (bid - 2048) & 511;
    src = wsel == 0 ? wq : wsel == 1 ? wk : wsel == 2 ? wv : wo;
    if (wsel == 0) sc = QSCALE;
    dst = wbase + (size_t)wsel * D_ * D_;
    i = wblk * 256 + threadIdx.x;
  }
  const float4* p = (const float4*)src + 2 * (size_t)i;
  float4 a = p[0], b = p[1];
  bf16x8 r = { (__bf16)(a.x*sc), (__bf16)(a.y*sc), (__bf16)(a.z*sc), (__bf16)(a.w*sc),
               (__bf16)(b.x*sc), (__bf16)(b.y*sc), (__bf16)(b.z*sc), (__bf16)(b.w*sc) };
  *((bf16x8*)dst + i) = r;
}

// ============ 128x256 BK=32 QKV GEMM, 8 waves, minimal-sync, 384 blocks ============
// (r19/r22 structure — measured best of all variants incl. triple-buffer r23.)
// z=2 (V) FUSION: epilogue writes directly in Vt[(b*16+h)*64+dh][t] layout,
// deleting the separate vt_k pass.
__global__ __launch_bounds__(512) void qkv8_k(const bf16_t* __restrict__ xb,
                                              const bf16_t* __restrict__ wqkv,
                                              bf16_t* __restrict__ Qbase,
                                              bf16_t* __restrict__ Vt) {
  __shared__ __align__(16) char lds[49152];
  const int z = blockIdx.z;
  const bf16_t* W = wqkv + (size_t)z * D_ * D_;
  bf16_t* C = Qbase + (size_t)z * M_ * D_;
  const int brow = blockIdx.x * 128, bcol = blockIdx.y * 256;

  const int tid = threadIdx.x;
  const int lane = tid & 63, w = tid >> 6;
  const int wm = w >> 2, wn = w & 3;
  const int lo = lane & 15, hi4 = lane >> 4;

  f32x4 acc[4][4];
  #pragma unroll
  for (int mi = 0; mi < 4; ++mi)
    #pragma unroll
    for (int ni = 0; ni < 4; ++ni) acc[mi][ni] = (f32x4){0.f, 0.f, 0.f, 0.f};

#define QSTAGE(T)                                                             \
  {                                                                           \
    char* base = lds + ((T) & 1) * 24576;                                     \
    const int kt = (T) * 32;                                                  \
    {                                                                         \
      int c = tid;                                                            \
      int row = c >> 2, sl = c & 3;                                           \
      int slg = sl ^ ((row >> 1) & 3);                                        \
      async16(xb + (size_t)(brow + row) * D_ + kt + slg * 8, base + c * 16);  \
    }                                                                         \
    _Pragma("unroll")                                                         \
    for (int i2 = 0; i2 < 2; ++i2) {                                          \
      int c = i2 * 512 + tid;                                                 \
      int row = c >> 2, sl = c & 3;                                           \
      int slg = sl ^ ((row >> 1) & 3);                                        \
      async16(W + (size_t)(bcol + row) * D_ + kt + slg * 8,                   \
              base + 8192 + c * 16);                                          \
    }                                                                         \
  }

  QSTAGE(0)

  const int nT = D_ / 32;
  for (int t = 0; t < nT; ++t) {
    const char* Ab = lds + (t & 1) * 24576;
    const char* Bb = Ab + 8192;

    if (t + 1 < nT) {
      QSTAGE(t + 1)
      asm volatile("s_waitcnt vmcnt(3)" ::: "memory");
    } else {
      asm volatile("s_waitcnt vmcnt(0)" ::: "memory");
    }
    __builtin_amdgcn_s_barrier();

    bf16x8 af[4], bf[4];
    #pragma unroll
    for (int mi = 0; mi < 4; ++mi) {
      int row = wm * 64 + mi * 16 + lo;
      af[mi] = *(const bf16x8*)(Ab + row * 64 + ((hi4 ^ ((row >> 1) & 3)) << 4));
    }
    #pragma unroll
    for (int ni = 0; ni < 4; ++ni) {
      int row = wn * 64 + ni * 16 + lo;
      bf[ni] = *(const bf16x8*)(Bb + row * 64 + ((hi4 ^ ((row >> 1) & 3)) << 4));
    }
    #pragma unroll
    for (int mi = 0; mi < 4; ++mi)
      #pragma unroll
      for (int ni = 0; ni < 4; ++ni)
        acc[mi][ni] = MFMA16(af[mi], bf[ni], acc[mi][ni]);

    __builtin_amdgcn_s_barrier();
  }
#undef QSTAGE

  if (z == 2) {
    // V slice: write transposed. b uniform per block (128 | 2048).
    const int b2 = brow >> 11;
    #pragma unroll
    for (int mi = 0; mi < 4; ++mi)
      #pragma unroll
      for (int ni = 0; ni < 4; ++ni) {
        int row = brow + wm * 64 + mi * 16 + hi4 * 4;   // V row (= b2*2048 + t0)
        int col = bcol + wn * 64 + ni * 16 + lo;        // V col (= h*64 + dh)
        int t0 = row & (T_ - 1);
        bf16_t* dst = Vt + ((size_t)((b2 * 16 + (col >> 6)) * 64 + (col & 63))) * T_ + t0;
        bf16x4 v = { (__bf16)acc[mi][ni][0], (__bf16)acc[mi][ni][1],
                     (__bf16)acc[mi][ni][2], (__bf16)acc[mi][ni][3] };
        *(bf16x4*)dst = v;
      }
  } else {
    #pragma unroll
    for (int mi = 0; mi < 4; ++mi)
      #pragma unroll
      for (int ni = 0; ni < 4; ++ni)
        #pragma unroll
        for (int i = 0; i < 4; ++i) {
          int row = brow + wm * 64 + mi * 16 + hi4 * 4 + i;
          int col = bcol + wn * 64 + ni * 16 + lo;
          C[(size_t)row * D_ + col] = (bf16_t)acc[mi][ni][i];
        }
  }
}

// ============ 64x128 BK=32 OUT GEMM, 4 waves, 512 blocks (r20, frozen) ============
__global__ __launch_bounds__(256) void out64_k(const bf16_t* __restrict__ O,
                                               const bf16_t* __restrict__ wob,
                                               float* __restrict__ Y) {
  __shared__ __align__(16) char lds[24576];
  const int brow = blockIdx.x * 64, bcol = blockIdx.y * 128;

  const int tid = threadIdx.x;
  const int lane = tid & 63, w = tid >> 6;
  const int wm = w >> 1, wn = w & 1;
  const int lo = lane & 15, hi4 = lane >> 4;

  f32x4 acc[2][4];
  #pragma unroll
  for (int mi = 0; mi < 2; ++mi)
    #pragma unroll
    for (int ni = 0; ni < 4; ++ni) acc[mi][ni] = (f32x4){0.f, 0.f, 0.f, 0.f};

#define OSTAGE(T)                                                             \
  {                                                                           \
    char* base = lds + ((T) & 1) * 12288;                                     \
    const int kt = (T) * 32;                                                  \
    {                                                                         \
      int c = tid;                                                            \
      int row = c >> 2, sl = c & 3;                                           \
      int slg = sl ^ ((row >> 1) & 3);                                        \
      async16(O + (size_t)(brow + row) * D_ + kt + slg * 8, base + c * 16);   \
    }                                                                         \
    _Pragma("unroll")                                                         \
    for (int i2 = 0; i2 < 2; ++i2) {                                          \
      int c = i2 * 256 + tid;                                                 \
      int row = c >> 2, sl = c & 3;                                           \
      int slg = sl ^ ((row >> 1) & 3);                                        \
      async16(wob + (size_t)(bcol + row) * D_ + kt + slg * 8,                 \
              base + 4096 + c * 16);                                          \
    }                                                                         \
  }

  OSTAGE(0)

  const int nT = D_ / 32;
  for (int t = 0; t < nT; ++t) {
    const char* Ab = lds + (t & 1) * 12288;
    const char* Bb = Ab + 4096;

    if (t + 1 < nT) {
      OSTAGE(t + 1)
      asm volatile("s_waitcnt vmcnt(3)" ::: "memory");
    } else {
      asm volatile("s_waitcnt vmcnt(0)" ::: "memory");
    }
    __builtin_amdgcn_s_barrier();

    bf16x8 af[2], bf[4];
    #pragma unroll
    for (int mi = 0; mi < 2; ++mi) {
      int row = wm * 32 + mi * 16 + lo;
      af[mi] = *(const bf16x8*)(Ab + row * 64 + ((hi4 ^ ((row >> 1) & 3)) << 4));
    }
    #pragma unroll
    for (int ni = 0; ni < 4; ++ni) {
      int row = wn * 64 + ni * 16 + lo;
      bf[ni] = *(const bf16x8*)(Bb + row * 64 + ((hi4 ^ ((row >> 1) & 3)) << 4));
    }
    #pragma unroll
    for (int mi = 0; mi < 2; ++mi)
      #pragma unroll
      for (int ni = 0; ni < 4; ++ni)
        acc[mi][ni] = MFMA16(af[mi], bf[ni], acc[mi][ni]);

    __builtin_amdgcn_s_barrier();
  }
#undef OSTAGE

  #pragma unroll
  for (int mi = 0; mi < 2; ++mi)
    #pragma unroll
    for (int ni = 0; ni < 4; ++ni)
      #pragma unroll
      for (int i = 0; i < 4; ++i) {
        int row = brow + wm * 32 + mi * 16 + hi4 * 4 + i;
        int col = bcol + wn * 64 + ni * 16 + lo;
        Y[(size_t)row * D_ + col] = acc[mi][ni][i];
      }
}

// ---------------- flash attention: r13 structure (proven 41.8-42.2us, FROZEN) ----------------
__global__ __launch_bounds__(512) void attn_k(const bf16_t* __restrict__ Q,
                                              const bf16_t* __restrict__ K,
                                              const bf16_t* __restrict__ Vt,
                                              bf16_t* __restrict__ O) {
  const int bh = blockIdx.x, b = bh >> 4, h = bh & 15;
  const int yy = (int)blockIdx.y;
  const int qt = (yy < 8) ? (15 - 2 * yy) : (30 - 2 * yy);
  const int tid = threadIdx.x;

  __shared__ __align__(16) char smem[65536];

  const bf16_t* Kt0 = K + ((size_t)b * T_) * D_ + h * 64;
  const bf16_t* Vt0 = Vt + (size_t)bh * 64 * T_;

  const int lane = tid & 63, w = tid >> 6;
  const int wl = w & 3, wg = w >> 2;
  const int ln = lane & 31, hi = lane >> 5;
  const int tl = tid & 255;
  const int tau = (ln & ~12) | (((ln & 4) << 1) | ((ln & 8) >> 1));
  char* sgbase = smem + ((tid >= 256) ? 32768 : 0);
  char* cgbase = smem + wg * 32768;
  float* mo = (float*)smem;
  float* ml = (float*)(smem + 33792);

  const int q_abs = qt * 128 + wl * 32 + ln;
  bf16x8 qf[4];
  {
    const bf16_t* Qrow = Q + ((size_t)b * T_ + q_abs) * D_ + h * 64;
    #pragma unroll
    for (int ks = 0; ks < 4; ++ks)
      qf[ks] = *(const bf16x8*)(Qrow + ks * 16 + hi * 8);
  }

  f32x16 o0 = zero16(), o1 = zero16();
  float m = -1e30f, l = 0.f;

  const int jc    = qt + 1;
  const int jd    = 2 * qt + (wl >> 1);
  const int tbase = wg ? (qt + 1) : 0;

#define STAGE8(BUF, TT)                                                       \
  {                                                                           \
    char* kd = sgbase + (BUF) * 8192;                                         \
    char* vd = sgbase + 16384 + (BUF) * 8192;                                 \
    _Pragma("unroll")                                                         \
    for (int it = 0; it < 2; ++it) {                                          \
      int c = it * 256 + tl;                                                  \
      int row = c >> 3, sl = c & 7;                                           \
      int slg = sl ^ (row & 7);                                               \
      async16(Kt0 + ((size_t)((TT) * 64 + row)) * D_ + slg * 8, kd + c * 16); \
      async16(Vt0 + (size_t)row * T_ + (TT) * 64 + slg * 8, vd + c * 16);     \
    }                                                                         \
  }

#define PACK_PV8(PS, KS, VB)                                                  \
  {                                                                           \
    const int r0 = ((KS) & 1) * 8;                                            \
    u32x4 pw = {pk2((PS)[r0 + 0], (PS)[r0 + 1]),                              \
                pk2((PS)[r0 + 2], (PS)[r0 + 3]),                              \
                pk2((PS)[r0 + 4], (PS)[r0 + 5]),                              \
                pk2((PS)[r0 + 6], (PS)[r0 + 7])};                             \
    bf16x8 pb = __builtin_bit_cast(bf16x8, pw);                               \
    const int sg = (KS) * 2 + hi;                                             \
    int row = ln;                                                             \
    bf16x8 vf0 = *(const bf16x8*)((VB) + row * 64 + ((sg ^ (row & 7)) * 8));  \
    o0 = MFMA32(vf0, pb, o0);                                                 \
    row = 32 + ln;                                                            \
    bf16x8 vf1 = *(const bf16x8*)((VB) + row * 64 + ((sg ^ (row & 7)) * 8));  \
    o1 = MFMA32(vf1, pb, o1);                                                 \
  }

  STAGE8(0, tbase)
  int cur = 0;
  for (int j = 0; j < jc; ++j) {
    if (j + 1 < jc) {
      STAGE8(cur ^ 1, tbase + j + 1)
      asm volatile("s_waitcnt vmcnt(4)" ::: "memory");
    } else {
      asm volatile("s_waitcnt vmcnt(0)" ::: "memory");
    }
    __builtin_amdgcn_s_barrier();

    const int tt = tbase + j;
    if (tt <= jd) {
      const bf16_t* Kb = (const bf16_t*)(cgbase + cur * 8192);
      const bf16_t* Vb = (const bf16_t*)(cgbase + 16384 + cur * 8192);
      f32x16 s0 = zero16(), s1 = zero16();
      __builtin_amdgcn_s_setprio(1);
      #pragma unroll
      for (int ks = 0; ks < 4; ++ks) {
        const int sg = ks * 2 + hi;
        int row = tau;
        bf16x8 kf0 = *(const bf16x8*)(Kb + row * 64 + ((sg ^ (row & 7)) * 8));
        s0 = MFMA32(kf0, qf[ks], s0);
        row = 32 + tau;
        bf16x8 kf1 = *(const bf16x8*)(Kb + row * 64 + ((sg ^ (row & 7)) * 8));
        s1 = MFMA32(kf1, qf[ks], s1);
      }
      __builtin_amdgcn_s_setprio(0);
      if (tt == jd) {
        const int kv0 = tt * 64;
        #pragma unroll
        for (int r = 0; r < 16; ++r) {
          const int pos = (r & 7) + 16 * (r >> 3) + 8 * hi;
          if (kv0 + pos      > q_abs) s0[r] = -3e38f;
          if (kv0 + 32 + pos > q_abs) s1[r] = -3e38f;
        }
      }
      float t[16];
      #pragma unroll
      for (int r = 0; r < 16; ++r) t[r] = fmaxf(s0[r], s1[r]);
      #pragma unroll
      for (int st = 8; st >= 1; st >>= 1)
        #pragma unroll
        for (int i = 0; i < st; ++i) t[i] = fmaxf(t[i], t[i + st]);
      float pmax = xswap_max(t[0]);
      if (!__all(pmax - m <= DEFER_THR)) {
        float mn   = fmaxf(m, pmax);
        float corr = EXP2(m - mn);
        m = mn;
        l *= corr;
        #pragma unroll
        for (int r = 0; r < 16; ++r) { o0[r] *= corr; o1[r] *= corr; }
      }
      float u[16];
      #pragma unroll
      for (int r = 0; r < 16; ++r) {
        float p0 = EXP2(s0[r] - m); s0[r] = p0;
        float p1 = EXP2(s1[r] - m); s1[r] = p1;
        u[r] = p0 + p1;
      }
      #pragma unroll
      for (int st = 8; st >= 1; st >>= 1)
        #pragma unroll
        for (int i = 0; i < st; ++i) u[i] += u[i + st];
      l += xswap_sum(u[0]);
      __builtin_amdgcn_s_setprio(1);
      PACK_PV8(s0, 0, Vb)
      PACK_PV8(s0, 1, Vb)
      PACK_PV8(s1, 2, Vb)
      PACK_PV8(s1, 3, Vb)
      __builtin_amdgcn_s_setprio(0);
    }
    __builtin_amdgcn_s_barrier();
    cur ^= 1;
  }

  if (wg == 1) {
    float* mop = mo + ((size_t)wl * 64 + lane) * 33;
    #pragma unroll
    for (int r = 0; r < 16; ++r) { mop[r] = o0[r]; mop[16 + r] = o1[r]; }
    float* mlp = ml + ((size_t)wl * 64 + lane) * 2;
    mlp[0] = m; mlp[1] = l;
  }
  __syncthreads();
  if (wg == 0) {
    const float* mop = mo + ((size_t)wl * 64 + lane) * 33;
    const float* mlp = ml + ((size_t)wl * 64 + lane) * 2;
    float mB = mlp[0], lB = mlp[1];
    float mS = fmaxf(m, mB);
    float cA = EXP2(m - mS), cB = EXP2(mB - mS);
    float lS = l * cA + lB * cB;
    float rl = 1.0f / lS;
    bf16_t* Orow = O + ((size_t)b * T_ + q_abs) * D_ + h * 64;
    #pragma unroll
    for (int g = 0; g < 4; ++g) {
      const int dh0 = 8 * g + 4 * hi;
      bf16x4 v0, v1;
      #pragma unroll
      for (int jj = 0; jj < 4; ++jj) {
        v0[jj] = (__bf16)((o0[4 * g + jj] * cA + mop[4 * g + jj] * cB) * rl);
        v1[jj] = (__bf16)((o1[4 * g + jj] * cA + mop[16 + 4 * g + jj] * cB) * rl);
      }
      *(bf16x4*)(Orow + dh0)      = v0;
      *(bf16x4*)(Orow + 32 + dh0) = v1;
    }
  }
#undef STAGE8
#undef PACK_PV8
}

// ---------------- launcher ----------------
extern "C" void kernel_launch(void* const* d_in, const int* in_sizes, int n_in,
                              void* d_out, int out_size, void* d_ws, size_t ws_size,
                              hipStream_t stream) {
  const float* x  = (const float*)d_in[0];
  const float* wq = (const float*)d_in[1];
  const float* wk = (const float*)d_in[2];
  const float* wv = (const float*)d_in[3];
  const float* wo = (const float*)d_in[4];
  float* out = (float*)d_out;

  char* ws = (char*)d_ws;
  bf16_t* xb  = (bf16_t*)(ws);                       // 8 MB
  bf16_t* wqb = (bf16_t*)(ws + (size_t)( 8 << 20));  // 2 MB each (contiguous qkv+o)
  bf16_t* wob = (bf16_t*)(ws + (size_t)(14 << 20));
  bf16_t* Qb  = (bf16_t*)(ws + (size_t)(16 << 20));  // 8 MB each, Q/K contiguous
  bf16_t* Kb  = (bf16_t*)(ws + (size_t)(24 << 20));
  bf16_t* Ob  = (bf16_t*)(ws + (size_t)(32 << 20));  // attn output
  bf16_t* Vtb = (bf16_t*)(ws + (size_t)(40 << 20));

  (void)in_sizes; (void)n_in; (void)out_size; (void)ws_size;

  cast_all_k<<<dim3(4096), 256, 0, stream>>>(x, wq, wk, wv, wo, xb, wqb);
  qkv8_k<<<dim3(M_ / 128, D_ / 256, 3), 512, 0, stream>>>(xb, wqb, Qb, Vtb);
  attn_k<<<dim3(B_ * H_, T_ / 128), 512, 0, stream>>>(Qb, Kb, Vtb, Ob);
  out64_k<<<dim3(M_ / 64, D_ / 128), 256, 0, stream>>>(Ob, wob, out);
}